// Round 3
// baseline (1156.930 us; speedup 1.0000x reference)
//
#include <hip/hip_runtime.h>
#include <math.h>

#define B 8
#define N 2048
#define D 1024

#define BM 128
#define BN 128
#define BK 32

typedef __bf16 bf16;
typedef __bf16 bf16x8 __attribute__((ext_vector_type(8)));
typedef __bf16 bf16x4 __attribute__((ext_vector_type(4)));
typedef float f32x4 __attribute__((ext_vector_type(4)));

__device__ __forceinline__ void load_lds16(const void* g, void* l) {
    __builtin_amdgcn_global_load_lds((const __attribute__((address_space(1))) void*)g,
                                     (__attribute__((address_space(3))) void*)l, 16, 0, 0);
}

// ---------------------------------------------------------------------------
// Split fp32 x into bf16 hi + lo residual (hi = RN(x), lo = RN(x - hi)).
// ---------------------------------------------------------------------------
__global__ __launch_bounds__(256) void split_fp32(const float* __restrict__ x,
                                                  bf16* __restrict__ h,
                                                  bf16* __restrict__ l, long n)
{
    long i = ((long)blockIdx.x * 256 + threadIdx.x) * 4;
    if (i >= n) return;
    float4 v = *(const float4*)(x + i);
    float vs[4] = {v.x, v.y, v.z, v.w};
    bf16x4 hh, ll;
#pragma unroll
    for (int t = 0; t < 4; ++t) {
        bf16 hv = (bf16)vs[t];
        hh[t] = hv;
        ll[t] = (bf16)(vs[t] - (float)hv);
    }
    *(bf16x4*)(h + i) = hh;
    *(bf16x4*)(l + i) = ll;
}

// ---------------------------------------------------------------------------
// Unified NT MFMA GEMM: C[i,j] = sum_k A[i,k] * Bm[j,k]  (both K-contracted
// row-major). 128x128 tile, BK=32, 256 threads = 2x2 waves of 4x4
// mfma_f32_16x16x32_bf16. TERMS: 1 = hi*hi only; 3 = split-bf16 3-term.
// EPI: 0 = write bf16 hi (+lo if Clo) ; 1 = write fp32 C ; 2 = PV epilogue
// (Out = C fp32, Feat = C + Text fp32).
// ---------------------------------------------------------------------------
template<int TERMS, int EPI>
__global__ __launch_bounds__(256) void gemm_nt_mfma(
    const bf16* __restrict__ Ah_g, const bf16* __restrict__ Al_g,
    const bf16* __restrict__ Bh_g, const bf16* __restrict__ Bl_g,
    bf16* __restrict__ Chi, bf16* __restrict__ Clo,
    float* __restrict__ Cf, const float* __restrict__ Text,
    float* __restrict__ Feat,
    int Mdim, int Ncdim, int Kdim, long sA, long sB, long sC)
{
    __shared__ bf16 Ah[BM][BK];
    __shared__ bf16 Bh[BN][BK];
    __shared__ bf16 Al[BM][BK];
    __shared__ bf16 Bl[BN][BK];

    const int tid = threadIdx.x;
    const int lane = tid & 63;
    const int wv = tid >> 6;
    const int wr = (wv >> 1) * 64;    // wave row offset in tile
    const int wc = (wv & 1) * 64;     // wave col offset in tile
    const int mfrag = lane & 15;
    const int quad = lane >> 4;

    const long z = blockIdx.z;
    const int row0 = blockIdx.y * BM;
    const int col0 = blockIdx.x * BN;

    const bf16* Abh = Ah_g + z * sA;
    const bf16* Abl = (TERMS == 3) ? (Al_g + z * sA) : nullptr;
    const bf16* Bbh = Bh_g + z * sB;
    const bf16* Bbl = (TERMS == 3) ? (Bl_g + z * sB) : nullptr;

    f32x4 acc[4][4] = {};

    for (int k0 = 0; k0 < Kdim; k0 += BK) {
#pragma unroll
        for (int q = 0; q < 2; ++q) {
            int c = q * 256 + tid;
            int row = c >> 2, kp = (c & 3) * 8;
            load_lds16(Abh + (long)(row0 + row) * Kdim + k0 + kp, &Ah[row][kp]);
            load_lds16(Bbh + (long)(col0 + row) * Kdim + k0 + kp, &Bh[row][kp]);
            if constexpr (TERMS == 3) {
                load_lds16(Abl + (long)(row0 + row) * Kdim + k0 + kp, &Al[row][kp]);
                load_lds16(Bbl + (long)(col0 + row) * Kdim + k0 + kp, &Bl[row][kp]);
            }
        }
        __syncthreads();

        bf16x8 a_h[4], b_h[4], a_l[4], b_l[4];
#pragma unroll
        for (int i = 0; i < 4; ++i) {
            a_h[i] = *(const bf16x8*)&Ah[wr + i * 16 + mfrag][quad * 8];
            b_h[i] = *(const bf16x8*)&Bh[wc + i * 16 + mfrag][quad * 8];
            if constexpr (TERMS == 3) {
                a_l[i] = *(const bf16x8*)&Al[wr + i * 16 + mfrag][quad * 8];
                b_l[i] = *(const bf16x8*)&Bl[wc + i * 16 + mfrag][quad * 8];
            }
        }
#pragma unroll
        for (int i = 0; i < 4; ++i)
#pragma unroll
            for (int j = 0; j < 4; ++j) {
                acc[i][j] = __builtin_amdgcn_mfma_f32_16x16x32_bf16(a_h[i], b_h[j], acc[i][j], 0, 0, 0);
                if constexpr (TERMS == 3) {
                    acc[i][j] = __builtin_amdgcn_mfma_f32_16x16x32_bf16(a_h[i], b_l[j], acc[i][j], 0, 0, 0);
                    acc[i][j] = __builtin_amdgcn_mfma_f32_16x16x32_bf16(a_l[i], b_h[j], acc[i][j], 0, 0, 0);
                }
            }
        __syncthreads();
    }

    // ---- epilogue ---- C/D layout: col = lane&15, row = quad*4 + reg
    const long cbase = z * sC;
    const bool wlo = (Clo != nullptr);
#pragma unroll
    for (int i = 0; i < 4; ++i) {
#pragma unroll
        for (int r = 0; r < 4; ++r) {
            int row = row0 + wr + i * 16 + quad * 4 + r;
#pragma unroll
            for (int j = 0; j < 4; ++j) {
                int col = col0 + wc + j * 16 + mfrag;
                long idx = cbase + (long)row * Ncdim + col;
                float v = acc[i][j][r];
                if constexpr (EPI == 0) {
                    bf16 h = (bf16)v;
                    Chi[idx] = h;
                    if (wlo) Clo[idx] = (bf16)(v - (float)h);
                } else if constexpr (EPI == 1) {
                    Cf[idx] = v;
                } else {
                    Cf[idx] = v;
                    Feat[idx] = v + Text[idx];
                }
            }
        }
    }
}

// ---------------------------------------------------------------------------
// Column softmax over the QUERY axis, fused online max+sum (single read pass)
// then a second pass writing alpha as bf16 to a separate buffer.
// S is [B][N(n)][N(m)] fp32; Aout is [B][N(n)][N(m)] bf16.
// One block = 64 columns (m) x 4 n-slices; coalesced across m.
// ---------------------------------------------------------------------------
__global__ __launch_bounds__(256) void col_softmax_bf16(const float* __restrict__ S,
                                                        bf16* __restrict__ Aout)
{
    const int b = blockIdx.x / (N / 64);
    const int mbase = (blockIdx.x % (N / 64)) * 64;
    const int t = threadIdx.x;
    const int mloc = t & 63;
    const int slice = t >> 6;             // 0..3
    const int m = mbase + mloc;
    const float* Sb = S + (size_t)b * N * N;
    bf16* Ab = Aout + (size_t)b * N * N;
    const int n_lo = slice * (N / 4), n_hi = n_lo + (N / 4);

    __shared__ float red_m[4][64];
    __shared__ float red_s[4][64];

    // pass 1: online max + rescaled sum (one read of S)
    float mx = -INFINITY, s = 0.0f;
    for (int n = n_lo; n < n_hi; ++n) {
        float x = Sb[(size_t)n * N + m];
        if (x > mx) {
            s = s * __expf(mx - x) + 1.0f;   // first iter: 0*exp(-inf)+1 = 1
            mx = x;
        } else {
            s += __expf(x - mx);
        }
    }
    red_m[slice][mloc] = mx;
    red_s[slice][mloc] = s;
    __syncthreads();

    float gm = fmaxf(fmaxf(red_m[0][mloc], red_m[1][mloc]),
                     fmaxf(red_m[2][mloc], red_m[3][mloc]));
    float den = red_s[0][mloc] * __expf(red_m[0][mloc] - gm)
              + red_s[1][mloc] * __expf(red_m[1][mloc] - gm)
              + red_s[2][mloc] * __expf(red_m[2][mloc] - gm)
              + red_s[3][mloc] * __expf(red_m[3][mloc] - gm);
    float inv = 1.0f / den;

    // pass 2: write alpha bf16
    for (int n = n_lo; n < n_hi; ++n) {
        size_t idx = (size_t)n * N + m;
        Ab[idx] = (bf16)(__expf(Sb[idx] - gm) * inv);
    }
}

// ---------------------------------------------------------------------------
extern "C" void kernel_launch(void* const* d_in, const int* in_sizes, int n_in,
                              void* d_out, int out_size, void* d_ws, size_t ws_size,
                              hipStream_t stream)
{
    const float* img  = (const float*)d_in[0];
    const float* text = (const float*)d_in[1];
    const float* Wq   = (const float*)d_in[2];
    const float* Wk   = (const float*)d_in[3];
    const float* Wv   = (const float*)d_in[4];

    float* out  = (float*)d_out;
    float* feat = out + (long)B * N * D;

    const long E  = (long)B * N * D;   // 16.78M elems
    const long W2 = (long)D * D;       // 1.05M elems
    const long EN = (long)B * N * N;   // 33.55M elems

    // ws layout (peak 180.4 MB, proven in round 2):
    //   [0 .. 2E*4)            img_h/img_l/text_h/text_l  -> later S fp32 (EN*4)
    //   [EN*4 ..)              Wq/Wk/Wv hi+lo (12.6 MB)
    //   [.. +E*2)              VT_h (33.5 MB)
    // d_out holds Q_h Q_l K_h K_l (4E bf16), all dead after QK^T.
    char* ws = (char*)d_ws;
    bf16* img_h  = (bf16*)ws;
    bf16* img_l  = img_h + E;
    bf16* text_h = img_l + E;
    bf16* text_l = text_h + E;
    float* S     = (float*)ws;             // aliases img/text splits (dead by then)
    bf16* Wq_h = (bf16*)(ws + (size_t)EN * 4);
    bf16* Wq_l = Wq_h + W2;
    bf16* Wk_h = Wq_l + W2;
    bf16* Wk_l = Wk_h + W2;
    bf16* Wv_h = Wk_l + W2;
    bf16* Wv_l = Wv_h + W2;
    bf16* VT_h = Wv_l + W2;
    char* ws_end = (char*)(VT_h + E);      // byte 180,355,072

    bf16* Q_h = (bf16*)d_out;
    bf16* Q_l = Q_h + E;
    bf16* K_h = Q_l + E;
    bf16* K_l = K_h + E;

    // alpha bf16 placement: in ws if it fits, else in dead Q half of d_out
    // (then PV's `out` goes to dead S-space in ws and is copied home).
    const size_t need_big = (size_t)(ws_end - ws) + (size_t)EN * 2;
    const bool big_ws = (ws_size >= need_big);
    bf16* alpha   = big_ws ? (bf16*)ws_end : (bf16*)d_out;   // 67 MB
    float* out_pv = big_ws ? out : (float*)ws;               // S-space is dead by PV

    dim3 blk(256);

    // 1. split inputs to bf16 hi/lo
    split_fp32<<<E / 1024, blk, 0, stream>>>(img,  img_h,  img_l,  E);
    split_fp32<<<E / 1024, blk, 0, stream>>>(text, text_h, text_l, E);
    split_fp32<<<W2 / 1024, blk, 0, stream>>>(Wq, Wq_h, Wq_l, W2);
    split_fp32<<<W2 / 1024, blk, 0, stream>>>(Wk, Wk_h, Wk_l, W2);
    split_fp32<<<W2 / 1024, blk, 0, stream>>>(Wv, Wv_h, Wv_l, W2);

    // 2. Q = img @ Wq^T, K = text @ Wk^T (3-term split-bf16, batch folded in M)
    gemm_nt_mfma<3, 0><<<dim3(D / BN, (B * N) / BM, 1), blk, 0, stream>>>(
        img_h, img_l, Wq_h, Wq_l, Q_h, Q_l, nullptr, nullptr, nullptr,
        B * N, D, D, 0, 0, 0);
    gemm_nt_mfma<3, 0><<<dim3(D / BN, (B * N) / BM, 1), blk, 0, stream>>>(
        text_h, text_l, Wk_h, Wk_l, K_h, K_l, nullptr, nullptr, nullptr,
        B * N, D, D, 0, 0, 0);

    // 3. VT[b][v][m] = sum_d Wv[v,d] * text[b,m,d]  (1-term, hi only)
    gemm_nt_mfma<1, 0><<<dim3(N / BN, D / BM, B), blk, 0, stream>>>(
        Wv_h, nullptr, text_h, nullptr, VT_h, nullptr, nullptr, nullptr, nullptr,
        D, N, D, 0, (long)N * D, (long)D * N);

    // 4. S[b] = Q[b] @ K[b]^T (3-term, fp32 out) — overwrites img/text splits
    gemm_nt_mfma<3, 1><<<dim3(N / BN, N / BM, B), blk, 0, stream>>>(
        Q_h, Q_l, K_h, K_l, nullptr, nullptr, S, nullptr, nullptr,
        N, N, D, (long)N * D, (long)N * D, (long)N * N);

    // 5. softmax over query axis; S fp32 -> alpha bf16 (Q/K in d_out now dead)
    col_softmax_bf16<<<dim3(B * N / 64), blk, 0, stream>>>(S, alpha);

    // 6. out[b][n][v] = sum_m alpha[b][n][m] * VT[b][v][m]; feat = out + text
    gemm_nt_mfma<1, 2><<<dim3(D / BN, N / BM, B), blk, 0, stream>>>(
        alpha, nullptr, VT_h, nullptr, nullptr, nullptr, out_pv, text, feat,
        N, D, N, (long)N * N, (long)D * N, (long)N * D);

    // 7. if out was computed into ws (alpha occupied d_out), copy it home
    if (!big_ws)
        hipMemcpyAsync(out, out_pv, (size_t)E * 4, hipMemcpyDeviceToDevice, stream);
}

// Round 4
// 983.926 us; speedup vs baseline: 1.1758x; 1.1758x over previous
//
#include <hip/hip_runtime.h>
#include <math.h>

#define B 8
#define N 2048
#define D 1024

#define BM 128
#define BN 128
#define BK 32

typedef __bf16 bf16;
typedef __bf16 bf16x8 __attribute__((ext_vector_type(8)));
typedef __bf16 bf16x4 __attribute__((ext_vector_type(4)));
typedef float f32x4 __attribute__((ext_vector_type(4)));

__device__ __forceinline__ void load_lds16(const void* g, void* l) {
    __builtin_amdgcn_global_load_lds((const __attribute__((address_space(1))) void*)g,
                                     (__attribute__((address_space(3))) void*)l, 16, 0, 0);
}

// ---------------------------------------------------------------------------
// Split fp32 x into bf16 hi + lo residual (hi = RN(x), lo = RN(x - hi)).
// ---------------------------------------------------------------------------
__global__ __launch_bounds__(256) void split_fp32(const float* __restrict__ x,
                                                  bf16* __restrict__ h,
                                                  bf16* __restrict__ l, long n)
{
    long i = ((long)blockIdx.x * 256 + threadIdx.x) * 4;
    if (i >= n) return;
    float4 v = *(const float4*)(x + i);
    float vs[4] = {v.x, v.y, v.z, v.w};
    bf16x4 hh, ll;
#pragma unroll
    for (int t = 0; t < 4; ++t) {
        bf16 hv = (bf16)vs[t];
        hh[t] = hv;
        ll[t] = (bf16)(vs[t] - (float)hv);
    }
    *(bf16x4*)(h + i) = hh;
    *(bf16x4*)(l + i) = ll;
}

// ---------------------------------------------------------------------------
// Unified NT MFMA GEMM: C[i,j] = sum_k A[i,k] * Bm[j,k]  (both K-contracted
// row-major). 128x128 tile, BK=32, 256 threads = 2x2 waves of 4x4
// mfma_f32_16x16x32_bf16. TERMS: 1 = hi*hi only; 3 = split-bf16 3-term.
// EPI: 0 = write bf16 hi (+lo if Clo) ; 1 = write fp32 C ; 2 = PV epilogue
// (Out = C fp32, Feat = C + Text fp32).
// ---------------------------------------------------------------------------
template<int TERMS, int EPI>
__global__ __launch_bounds__(256) void gemm_nt_mfma(
    const bf16* __restrict__ Ah_g, const bf16* __restrict__ Al_g,
    const bf16* __restrict__ Bh_g, const bf16* __restrict__ Bl_g,
    bf16* __restrict__ Chi, bf16* __restrict__ Clo,
    float* __restrict__ Cf, const float* __restrict__ Text,
    float* __restrict__ Feat,
    int Mdim, int Ncdim, int Kdim, long sA, long sB, long sC)
{
    __shared__ bf16 Ah[BM][BK];
    __shared__ bf16 Bh[BN][BK];
    __shared__ bf16 Al[BM][BK];
    __shared__ bf16 Bl[BN][BK];

    const int tid = threadIdx.x;
    const int lane = tid & 63;
    const int wv = tid >> 6;
    const int wr = (wv >> 1) * 64;    // wave row offset in tile
    const int wc = (wv & 1) * 64;     // wave col offset in tile
    const int mfrag = lane & 15;
    const int quad = lane >> 4;

    const long z = blockIdx.z;
    const int row0 = blockIdx.y * BM;
    const int col0 = blockIdx.x * BN;

    const bf16* Abh = Ah_g + z * sA;
    const bf16* Abl = (TERMS == 3) ? (Al_g + z * sA) : nullptr;
    const bf16* Bbh = Bh_g + z * sB;
    const bf16* Bbl = (TERMS == 3) ? (Bl_g + z * sB) : nullptr;

    f32x4 acc[4][4] = {};

    for (int k0 = 0; k0 < Kdim; k0 += BK) {
#pragma unroll
        for (int q = 0; q < 2; ++q) {
            int c = q * 256 + tid;
            int row = c >> 2, kp = (c & 3) * 8;
            load_lds16(Abh + (long)(row0 + row) * Kdim + k0 + kp, &Ah[row][kp]);
            load_lds16(Bbh + (long)(col0 + row) * Kdim + k0 + kp, &Bh[row][kp]);
            if constexpr (TERMS == 3) {
                load_lds16(Abl + (long)(row0 + row) * Kdim + k0 + kp, &Al[row][kp]);
                load_lds16(Bbl + (long)(col0 + row) * Kdim + k0 + kp, &Bl[row][kp]);
            }
        }
        __syncthreads();

        bf16x8 a_h[4], b_h[4], a_l[4], b_l[4];
#pragma unroll
        for (int i = 0; i < 4; ++i) {
            a_h[i] = *(const bf16x8*)&Ah[wr + i * 16 + mfrag][quad * 8];
            b_h[i] = *(const bf16x8*)&Bh[wc + i * 16 + mfrag][quad * 8];
            if constexpr (TERMS == 3) {
                a_l[i] = *(const bf16x8*)&Al[wr + i * 16 + mfrag][quad * 8];
                b_l[i] = *(const bf16x8*)&Bl[wc + i * 16 + mfrag][quad * 8];
            }
        }
#pragma unroll
        for (int i = 0; i < 4; ++i)
#pragma unroll
            for (int j = 0; j < 4; ++j) {
                acc[i][j] = __builtin_amdgcn_mfma_f32_16x16x32_bf16(a_h[i], b_h[j], acc[i][j], 0, 0, 0);
                if constexpr (TERMS == 3) {
                    acc[i][j] = __builtin_amdgcn_mfma_f32_16x16x32_bf16(a_h[i], b_l[j], acc[i][j], 0, 0, 0);
                    acc[i][j] = __builtin_amdgcn_mfma_f32_16x16x32_bf16(a_l[i], b_h[j], acc[i][j], 0, 0, 0);
                }
            }
        __syncthreads();
    }

    // ---- epilogue ---- C/D layout: col = lane&15, row = quad*4 + reg
    const long cbase = z * sC;
    const bool wlo = (Clo != nullptr);
#pragma unroll
    for (int i = 0; i < 4; ++i) {
#pragma unroll
        for (int r = 0; r < 4; ++r) {
            int row = row0 + wr + i * 16 + quad * 4 + r;
#pragma unroll
            for (int j = 0; j < 4; ++j) {
                int col = col0 + wc + j * 16 + mfrag;
                long idx = cbase + (long)row * Ncdim + col;
                float v = acc[i][j][r];
                if constexpr (EPI == 0) {
                    bf16 h = (bf16)v;
                    Chi[idx] = h;
                    if (wlo) Clo[idx] = (bf16)(v - (float)h);
                } else if constexpr (EPI == 1) {
                    Cf[idx] = v;
                } else {
                    Cf[idx] = v;
                    Feat[idx] = v + Text[idx];
                }
            }
        }
    }
}

// ---------------------------------------------------------------------------
// Column softmax over the QUERY axis, throughput version.
// S is [B][N(n)][N(m)] fp32; Aout [B][N][N] bf16.
// Block = 1024 threads = 64 columns (m) x 16 n-slices; 8x-unrolled loads for
// MLP; branchless online max+sum. Grid = B * N/64 = 256 blocks, 16 waves each
// -> 50% occupancy cap (vs 12.5% in the round-3 version).
// ---------------------------------------------------------------------------
__global__ __launch_bounds__(1024) void col_softmax_bf16(const float* __restrict__ S,
                                                         bf16* __restrict__ Aout)
{
    const int b = blockIdx.x / (N / 64);
    const int mbase = (blockIdx.x % (N / 64)) * 64;
    const int t = threadIdx.x;
    const int mloc = t & 63;
    const int slice = t >> 6;             // 0..15
    const int m = mbase + mloc;
    const float* Sb = S + (size_t)b * N * N;
    bf16* Ab = Aout + (size_t)b * N * N;
    const int n_lo = slice * (N / 16), n_hi = n_lo + (N / 16);   // 128 rows

    __shared__ float red_m[16][64];
    __shared__ float red_s[16][64];

    // pass 1: branchless online max + rescaled sum, 8x unrolled
    float mx = -INFINITY, s = 0.0f;
    for (int n = n_lo; n < n_hi; n += 8) {
        float x[8];
#pragma unroll
        for (int u = 0; u < 8; ++u) x[u] = Sb[(size_t)(n + u) * N + m];
        float bm = x[0];
#pragma unroll
        for (int u = 1; u < 8; ++u) bm = fmaxf(bm, x[u]);
        float nm = fmaxf(mx, bm);
        float a = 0.0f;
#pragma unroll
        for (int u = 0; u < 8; ++u) a += __expf(x[u] - nm);
        s = s * __expf(mx - nm) + a;      // first group: 0 * exp(-inf) = 0
        mx = nm;
    }
    red_m[slice][mloc] = mx;
    red_s[slice][mloc] = s;
    __syncthreads();

    float gm = -INFINITY;
#pragma unroll
    for (int i = 0; i < 16; ++i) gm = fmaxf(gm, red_m[i][mloc]);
    float den = 0.0f;
#pragma unroll
    for (int i = 0; i < 16; ++i) den += red_s[i][mloc] * __expf(red_m[i][mloc] - gm);
    float inv = 1.0f / den;

    // pass 2: write alpha bf16, 8x unrolled
    for (int n = n_lo; n < n_hi; n += 8) {
        float x[8];
#pragma unroll
        for (int u = 0; u < 8; ++u) x[u] = Sb[(size_t)(n + u) * N + m];
#pragma unroll
        for (int u = 0; u < 8; ++u)
            Ab[(size_t)(n + u) * N + m] = (bf16)(__expf(x[u] - gm) * inv);
    }
}

// ---------------------------------------------------------------------------
extern "C" void kernel_launch(void* const* d_in, const int* in_sizes, int n_in,
                              void* d_out, int out_size, void* d_ws, size_t ws_size,
                              hipStream_t stream)
{
    const float* img  = (const float*)d_in[0];
    const float* text = (const float*)d_in[1];
    const float* Wq   = (const float*)d_in[2];
    const float* Wk   = (const float*)d_in[3];
    const float* Wv   = (const float*)d_in[4];

    float* out  = (float*)d_out;
    float* feat = out + (long)B * N * D;

    const long E  = (long)B * N * D;   // 16.78M elems
    const long W2 = (long)D * D;       // 1.05M elems
    const long EN = (long)B * N * N;   // 33.55M elems

    // ws layout (peak 180.4 MB, proven):
    //   [0 .. 2E*4)            img_h/img_l/text_h/text_l  -> later S fp32 (EN*4)
    //   [EN*4 ..)              Wq/Wk/Wv hi+lo (12.6 MB)
    //   [.. +E*2)              VT_h (33.5 MB)
    // d_out holds Q_h Q_l K_h K_l (4E bf16), all dead after QK^T.
    char* ws = (char*)d_ws;
    bf16* img_h  = (bf16*)ws;
    bf16* img_l  = img_h + E;
    bf16* text_h = img_l + E;
    bf16* text_l = text_h + E;
    float* S     = (float*)ws;             // aliases img/text splits (dead by then)
    bf16* Wq_h = (bf16*)(ws + (size_t)EN * 4);
    bf16* Wq_l = Wq_h + W2;
    bf16* Wk_h = Wq_l + W2;
    bf16* Wk_l = Wk_h + W2;
    bf16* Wv_h = Wk_l + W2;
    bf16* Wv_l = Wv_h + W2;
    bf16* VT_h = Wv_l + W2;
    char* ws_end = (char*)(VT_h + E);      // byte 180,355,072

    bf16* Q_h = (bf16*)d_out;
    bf16* Q_l = Q_h + E;
    bf16* K_h = Q_l + E;
    bf16* K_l = K_h + E;

    // alpha bf16 placement: in ws if it fits, else in dead Q half of d_out
    // (then PV's `out` goes to dead S-space in ws and is copied home).
    const size_t need_big = (size_t)(ws_end - ws) + (size_t)EN * 2;
    const bool big_ws = (ws_size >= need_big);
    bf16* alpha   = big_ws ? (bf16*)ws_end : (bf16*)d_out;   // 67 MB
    float* out_pv = big_ws ? out : (float*)ws;               // S-space is dead by PV

    dim3 blk(256);

    // 1. split inputs to bf16 hi/lo
    split_fp32<<<E / 1024, blk, 0, stream>>>(img,  img_h,  img_l,  E);
    split_fp32<<<E / 1024, blk, 0, stream>>>(text, text_h, text_l, E);
    split_fp32<<<W2 / 1024, blk, 0, stream>>>(Wq, Wq_h, Wq_l, W2);
    split_fp32<<<W2 / 1024, blk, 0, stream>>>(Wk, Wk_h, Wk_l, W2);
    split_fp32<<<W2 / 1024, blk, 0, stream>>>(Wv, Wv_h, Wv_l, W2);

    // 2. Q = img @ Wq^T, K = text @ Wk^T (3-term split-bf16, batch folded in M)
    gemm_nt_mfma<3, 0><<<dim3(D / BN, (B * N) / BM, 1), blk, 0, stream>>>(
        img_h, img_l, Wq_h, Wq_l, Q_h, Q_l, nullptr, nullptr, nullptr,
        B * N, D, D, 0, 0, 0);
    gemm_nt_mfma<3, 0><<<dim3(D / BN, (B * N) / BM, 1), blk, 0, stream>>>(
        text_h, text_l, Wk_h, Wk_l, K_h, K_l, nullptr, nullptr, nullptr,
        B * N, D, D, 0, 0, 0);

    // 3. VT[b][v][m] = sum_d Wv[v,d] * text[b,m,d]  (1-term, hi only)
    gemm_nt_mfma<1, 0><<<dim3(N / BN, D / BM, B), blk, 0, stream>>>(
        Wv_h, nullptr, text_h, nullptr, VT_h, nullptr, nullptr, nullptr, nullptr,
        D, N, D, 0, (long)N * D, (long)D * N);

    // 4. S[b] = Q[b] @ K[b]^T (3-term, fp32 out) — overwrites img/text splits
    gemm_nt_mfma<3, 1><<<dim3(N / BN, N / BM, B), blk, 0, stream>>>(
        Q_h, Q_l, K_h, K_l, nullptr, nullptr, S, nullptr, nullptr,
        N, N, D, (long)N * D, (long)N * D, (long)N * N);

    // 5. softmax over query axis; S fp32 -> alpha bf16 (Q/K in d_out now dead)
    col_softmax_bf16<<<dim3(B * N / 64), dim3(1024), 0, stream>>>(S, alpha);

    // 6. out[b][n][v] = sum_m alpha[b][n][m] * VT[b][v][m]; feat = out + text
    gemm_nt_mfma<1, 2><<<dim3(D / BN, N / BM, B), blk, 0, stream>>>(
        alpha, nullptr, VT_h, nullptr, nullptr, nullptr, out_pv, text, feat,
        N, D, N, (long)N * N, (long)D * N, (long)N * D);

    // 7. if out was computed into ws (alpha occupied d_out), copy it home
    if (!big_ws)
        hipMemcpyAsync(out, out_pv, (size_t)E * 4, hipMemcpyDeviceToDevice, stream);
}

// Round 5
// 934.500 us; speedup vs baseline: 1.2380x; 1.0529x over previous
//
#include <hip/hip_runtime.h>
#include <math.h>

#define B 8
#define N 2048
#define D 1024

#define BM 128
#define BN 128
#define BK 32

typedef __bf16 bf16;
typedef __bf16 bf16x8 __attribute__((ext_vector_type(8)));
typedef __bf16 bf16x4 __attribute__((ext_vector_type(4)));
typedef float f32x4 __attribute__((ext_vector_type(4)));

__device__ __forceinline__ void load_lds16(const void* g, void* l) {
    __builtin_amdgcn_global_load_lds((const __attribute__((address_space(1))) void*)g,
                                     (__attribute__((address_space(3))) void*)l, 16, 0, 0);
}

// ---------------------------------------------------------------------------
// Split fp32 x into bf16 hi + lo residual (hi = RN(x), lo = RN(x - hi)).
// ---------------------------------------------------------------------------
__global__ __launch_bounds__(256) void split_fp32(const float* __restrict__ x,
                                                  bf16* __restrict__ h,
                                                  bf16* __restrict__ l, long n)
{
    long i = ((long)blockIdx.x * 256 + threadIdx.x) * 4;
    if (i >= n) return;
    float4 v = *(const float4*)(x + i);
    float vs[4] = {v.x, v.y, v.z, v.w};
    bf16x4 hh, ll;
#pragma unroll
    for (int t = 0; t < 4; ++t) {
        bf16 hv = (bf16)vs[t];
        hh[t] = hv;
        ll[t] = (bf16)(vs[t] - (float)hv);
    }
    *(bf16x4*)(h + i) = hh;
    *(bf16x4*)(l + i) = ll;
}

// ---------------------------------------------------------------------------
// Transpose + split: in W [1024][1024] fp32 row-major -> WT_h/WT_l [1024][1024]
// bf16 with WT[d][k] = W[k][d]. LDS-tiled 64x64, both sides coalesced.
// ---------------------------------------------------------------------------
__global__ __launch_bounds__(256) void tsplit_1024(const float* __restrict__ W,
                                                   bf16* __restrict__ WT_h,
                                                   bf16* __restrict__ WT_l)
{
    __shared__ float tile[64][65];
    const int d0 = blockIdx.x * 64, k0 = blockIdx.y * 64;
    const int tx = threadIdx.x & 63, ty = threadIdx.x >> 6;   // tx: fast dim
#pragma unroll
    for (int r = 0; r < 16; ++r) {
        int kl = ty + r * 4;
        tile[kl][tx] = W[(size_t)(k0 + kl) * 1024 + d0 + tx];
    }
    __syncthreads();
#pragma unroll
    for (int r = 0; r < 16; ++r) {
        int dl = ty + r * 4;
        float v = tile[tx][dl];
        bf16 hv = (bf16)v;
        size_t idx = (size_t)(d0 + dl) * 1024 + k0 + tx;
        WT_h[idx] = hv;
        WT_l[idx] = (bf16)(v - (float)hv);
    }
}

// ---------------------------------------------------------------------------
// Unified NT MFMA GEMM: C[i,j] = sum_k A[i,k] * Bm[j,k]  (both K-contracted
// row-major). 128x128 tile, BK=32, 256 threads = 2x2 waves of 4x4
// mfma_f32_16x16x32_bf16. TERMS: 1 = hi*hi only; 3 = split-bf16 3-term.
// EPI: 0 = write bf16 hi (+lo if Clo) ; 1 = write fp32 C ; 2 = PV epilogue
// (Out = C fp32, Feat = C + Text fp32).
// ---------------------------------------------------------------------------
template<int TERMS, int EPI>
__global__ __launch_bounds__(256) void gemm_nt_mfma(
    const bf16* __restrict__ Ah_g, const bf16* __restrict__ Al_g,
    const bf16* __restrict__ Bh_g, const bf16* __restrict__ Bl_g,
    bf16* __restrict__ Chi, bf16* __restrict__ Clo,
    float* __restrict__ Cf, const float* __restrict__ Text,
    float* __restrict__ Feat,
    int Mdim, int Ncdim, int Kdim, long sA, long sB, long sC)
{
    __shared__ bf16 Ah[BM][BK];
    __shared__ bf16 Bh[BN][BK];
    __shared__ bf16 Al[BM][BK];
    __shared__ bf16 Bl[BN][BK];

    const int tid = threadIdx.x;
    const int lane = tid & 63;
    const int wv = tid >> 6;
    const int wr = (wv >> 1) * 64;    // wave row offset in tile
    const int wc = (wv & 1) * 64;     // wave col offset in tile
    const int mfrag = lane & 15;
    const int quad = lane >> 4;

    const long z = blockIdx.z;
    const int row0 = blockIdx.y * BM;
    const int col0 = blockIdx.x * BN;

    const bf16* Abh = Ah_g + z * sA;
    const bf16* Abl = (TERMS == 3) ? (Al_g + z * sA) : nullptr;
    const bf16* Bbh = Bh_g + z * sB;
    const bf16* Bbl = (TERMS == 3) ? (Bl_g + z * sB) : nullptr;

    f32x4 acc[4][4] = {};

    for (int k0 = 0; k0 < Kdim; k0 += BK) {
#pragma unroll
        for (int q = 0; q < 2; ++q) {
            int c = q * 256 + tid;
            int row = c >> 2, kp = (c & 3) * 8;
            load_lds16(Abh + (long)(row0 + row) * Kdim + k0 + kp, &Ah[row][kp]);
            load_lds16(Bbh + (long)(col0 + row) * Kdim + k0 + kp, &Bh[row][kp]);
            if constexpr (TERMS == 3) {
                load_lds16(Abl + (long)(row0 + row) * Kdim + k0 + kp, &Al[row][kp]);
                load_lds16(Bbl + (long)(col0 + row) * Kdim + k0 + kp, &Bl[row][kp]);
            }
        }
        __syncthreads();

        bf16x8 a_h[4], b_h[4], a_l[4], b_l[4];
#pragma unroll
        for (int i = 0; i < 4; ++i) {
            a_h[i] = *(const bf16x8*)&Ah[wr + i * 16 + mfrag][quad * 8];
            b_h[i] = *(const bf16x8*)&Bh[wc + i * 16 + mfrag][quad * 8];
            if constexpr (TERMS == 3) {
                a_l[i] = *(const bf16x8*)&Al[wr + i * 16 + mfrag][quad * 8];
                b_l[i] = *(const bf16x8*)&Bl[wc + i * 16 + mfrag][quad * 8];
            }
        }
#pragma unroll
        for (int i = 0; i < 4; ++i)
#pragma unroll
            for (int j = 0; j < 4; ++j) {
                acc[i][j] = __builtin_amdgcn_mfma_f32_16x16x32_bf16(a_h[i], b_h[j], acc[i][j], 0, 0, 0);
                if constexpr (TERMS == 3) {
                    acc[i][j] = __builtin_amdgcn_mfma_f32_16x16x32_bf16(a_h[i], b_l[j], acc[i][j], 0, 0, 0);
                    acc[i][j] = __builtin_amdgcn_mfma_f32_16x16x32_bf16(a_l[i], b_h[j], acc[i][j], 0, 0, 0);
                }
            }
        __syncthreads();
    }

    // ---- epilogue ---- C/D layout: col = lane&15, row = quad*4 + reg
    const long cbase = z * sC;
    const bool wlo = (Clo != nullptr);
#pragma unroll
    for (int i = 0; i < 4; ++i) {
#pragma unroll
        for (int r = 0; r < 4; ++r) {
            int row = row0 + wr + i * 16 + quad * 4 + r;
#pragma unroll
            for (int j = 0; j < 4; ++j) {
                int col = col0 + wc + j * 16 + mfrag;
                long idx = cbase + (long)row * Ncdim + col;
                float v = acc[i][j][r];
                if constexpr (EPI == 0) {
                    bf16 h = (bf16)v;
                    Chi[idx] = h;
                    if (wlo) Clo[idx] = (bf16)(v - (float)h);
                } else if constexpr (EPI == 1) {
                    Cf[idx] = v;
                } else {
                    Cf[idx] = v;
                    Feat[idx] = v + Text[idx];
                }
            }
        }
    }
}

// ---------------------------------------------------------------------------
// Column softmax over the QUERY axis, throughput version (round-4 verified).
// Block = 1024 threads = 64 columns x 16 n-slices; 8x-unrolled loads.
// ---------------------------------------------------------------------------
__global__ __launch_bounds__(1024) void col_softmax_bf16(const float* __restrict__ S,
                                                         bf16* __restrict__ Aout)
{
    const int b = blockIdx.x / (N / 64);
    const int mbase = (blockIdx.x % (N / 64)) * 64;
    const int t = threadIdx.x;
    const int mloc = t & 63;
    const int slice = t >> 6;             // 0..15
    const int m = mbase + mloc;
    const float* Sb = S + (size_t)b * N * N;
    bf16* Ab = Aout + (size_t)b * N * N;
    const int n_lo = slice * (N / 16), n_hi = n_lo + (N / 16);   // 128 rows

    __shared__ float red_m[16][64];
    __shared__ float red_s[16][64];

    float mx = -INFINITY, s = 0.0f;
    for (int n = n_lo; n < n_hi; n += 8) {
        float x[8];
#pragma unroll
        for (int u = 0; u < 8; ++u) x[u] = Sb[(size_t)(n + u) * N + m];
        float bm = x[0];
#pragma unroll
        for (int u = 1; u < 8; ++u) bm = fmaxf(bm, x[u]);
        float nm = fmaxf(mx, bm);
        float a = 0.0f;
#pragma unroll
        for (int u = 0; u < 8; ++u) a += __expf(x[u] - nm);
        s = s * __expf(mx - nm) + a;
        mx = nm;
    }
    red_m[slice][mloc] = mx;
    red_s[slice][mloc] = s;
    __syncthreads();

    float gm = -INFINITY;
#pragma unroll
    for (int i = 0; i < 16; ++i) gm = fmaxf(gm, red_m[i][mloc]);
    float den = 0.0f;
#pragma unroll
    for (int i = 0; i < 16; ++i) den += red_s[i][mloc] * __expf(red_m[i][mloc] - gm);
    float inv = 1.0f / den;

    for (int n = n_lo; n < n_hi; n += 8) {
        float x[8];
#pragma unroll
        for (int u = 0; u < 8; ++u) x[u] = Sb[(size_t)(n + u) * N + m];
#pragma unroll
        for (int u = 0; u < 8; ++u)
            Ab[(size_t)(n + u) * N + m] = (bf16)(__expf(x[u] - gm) * inv);
    }
}

// ---------------------------------------------------------------------------
extern "C" void kernel_launch(void* const* d_in, const int* in_sizes, int n_in,
                              void* d_out, int out_size, void* d_ws, size_t ws_size,
                              hipStream_t stream)
{
    const float* img  = (const float*)d_in[0];
    const float* text = (const float*)d_in[1];
    const float* Wq   = (const float*)d_in[2];
    const float* Wk   = (const float*)d_in[3];
    const float* Wv   = (const float*)d_in[4];

    const long E  = (long)B * N * D;   // 16.78M
    const long W2 = (long)D * D;       // 1.05M
    const long EN = (long)B * N * N;   // 33.55M

    // S = img @ (Wq^T Wk) @ text^T  -- Q/K projections folded into a 1024x1024
    // weight product. ws usage: exactly 201.3 MB (proven in round 1).
    //
    // ws region A [0 .. EN*4): S fp32; aliased earlier (all dead before S) by
    //   img_h/img_l and W scratch. Also out_pv (PV output) after softmax.
    // ws region B [EN*4 .. EN*4+4E): text_h, text_l; text_l's spot recycled
    //   for VT_h after the S GEMM.
    // d_out: T_h, T_l, Wv_h during the mid-pipeline; alpha + feat at the end.
    char* ws = (char*)d_ws;
    float* S     = (float*)ws;
    bf16* img_h  = (bf16*)ws;
    bf16* img_l  = img_h + E;
    bf16* WqT_h  = (bf16*)(ws + (size_t)4 * E);
    bf16* WqT_l  = WqT_h + W2;
    bf16* WkT_h  = WqT_l + W2;
    bf16* WkT_l  = WkT_h + W2;
    bf16* Wqk_h  = WkT_l + W2;
    bf16* Wqk_l  = Wqk_h + W2;
    bf16* Wv_l_s = Wqk_l + W2;             // scratch lo for Wv (unused after)
    float* out_pv = (float*)ws;            // S region, dead after softmax

    bf16* text_h = (bf16*)(ws + (size_t)EN * 4);
    bf16* text_l = text_h + E;
    bf16* VT_h   = text_l;                 // recycled after S GEMM

    bf16* T_h  = (bf16*)d_out;
    bf16* T_l  = T_h + E;
    bf16* Wv_h = T_l + E;                  // d_out bytes [4E .. 4E+2*W2)
    bf16* alpha = (bf16*)d_out;            // overwrites T after S GEMM
    float* out  = (float*)d_out;
    float* feat = out + E;                 // d_out bytes [4E .. 8E)

    dim3 blk(256);

    // 1. splits
    split_fp32<<<E / 1024, blk, 0, stream>>>(img,  img_h,  img_l,  E);
    split_fp32<<<E / 1024, blk, 0, stream>>>(text, text_h, text_l, E);
    split_fp32<<<W2 / 1024, blk, 0, stream>>>(Wv, Wv_h, Wv_l_s, W2);
    tsplit_1024<<<dim3(16, 16), blk, 0, stream>>>(Wq, WqT_h, WqT_l);
    tsplit_1024<<<dim3(16, 16), blk, 0, stream>>>(Wk, WkT_h, WkT_l);

    // 2. Wqk'[i,j] = sum_k Wk[k,i] * Wq[k,j]   (= (Wq^T Wk) transposed, which
    //    is exactly the NT B-operand layout the T GEMM needs)
    gemm_nt_mfma<3, 0><<<dim3(8, 8, 1), blk, 0, stream>>>(
        WkT_h, WkT_l, WqT_h, WqT_l, Wqk_h, Wqk_l, nullptr, nullptr, nullptr,
        D, D, D, 0, 0, 0);

    // 3. T = img @ Wqk  (split out to T_h/T_l in d_out)
    gemm_nt_mfma<3, 0><<<dim3(D / BN, (B * N) / BM, 1), blk, 0, stream>>>(
        img_h, img_l, Wqk_h, Wqk_l, T_h, T_l, nullptr, nullptr, nullptr,
        B * N, D, D, 0, 0, 0);

    // 4. S[b] = T[b] @ text[b]^T  (3-term, fp32) — overwrites img/W scratch
    gemm_nt_mfma<3, 1><<<dim3(N / BN, N / BM, B), blk, 0, stream>>>(
        T_h, T_l, text_h, text_l, nullptr, nullptr, S, nullptr, nullptr,
        N, N, D, (long)N * D, (long)N * D, (long)N * N);

    // 5. VT[b][v][m] = sum_d Wv[v,d] * text[b,m,d] (1-term; writes over text_l)
    gemm_nt_mfma<1, 0><<<dim3(N / BN, D / BM, B), blk, 0, stream>>>(
        Wv_h, nullptr, text_h, nullptr, VT_h, nullptr, nullptr, nullptr, nullptr,
        D, N, D, 0, (long)N * D, (long)D * N);

    // 6. softmax over query axis; S fp32 -> alpha bf16 (T in d_out now dead)
    col_softmax_bf16<<<dim3(B * N / 64), dim3(1024), 0, stream>>>(S, alpha);

    // 7. out[b][n][v] = sum_m alpha[b][n][m] * VT[b][v][m]; feat = out + text
    gemm_nt_mfma<1, 2><<<dim3(D / BN, N / BM, B), blk, 0, stream>>>(
        alpha, nullptr, VT_h, nullptr, nullptr, nullptr, out_pv, text, feat,
        N, D, N, (long)N * N, (long)D * N, (long)N * D);

    // 8. move `out` home (alpha occupied d_out[0..4E) during PV)
    hipMemcpyAsync(out, out_pv, (size_t)E * 4, hipMemcpyDeviceToDevice, stream);
}